// Round 15
// baseline (280.900 us; speedup 1.0000x reference)
//
#include <hip/hip_runtime.h>
#include <math.h>

#define B 256
#define D 256
#define M 100000
#define C 5000
#define TEMPF 0.05f
#define EPSF 1e-6f
#define NCB 79          // ceil(C/64)
#define SPITCH 80       // padded partial-sum pitch

// ---- float ws layout (float offsets) ----
#define OFF_G 0                       // C*D = 1,280,000
#define OFF_NUMS (C * D)              // 5120
#define OFF_X (OFF_NUMS + 5120)       // B*D = 65,536
#define OFF_SPART (OFF_X + B * D)     // B*SPITCH = 20,480
#define OFF_I (OFF_SPART + B * SPITCH)
// ---- int region (int offsets from OFF_I) ----
#define I_STARTS 0                    // C+1
#define I_CURSOR (C + 1)              // C
#define I_PERM (C + 1 + C)            // M
#define I_TOTAL (I_PERM + M)
#define WS_NEED ((size_t)OFF_I * 4 + (size_t)I_TOTAL * 4)   // ~5.9 MB

// ========== fused histogram + exclusive scan (1 block, counts in LDS) =======
__global__ __launch_bounds__(1024) void k_histscan(const int* __restrict__ labels,
                                                   float* __restrict__ ws) {
    __shared__ int cnt[5120];
    __shared__ int sh[1024];
    const int t = threadIdx.x;
    for (int i = t; i < 5120; i += 1024) cnt[i] = 0;
    __syncthreads();
    for (int m = t; m < M; m += 1024) atomicAdd(&cnt[labels[m]], 1);
    __syncthreads();
    // chunked scan: 1024 threads x 5 = 5120 >= C
    const int lo = t * 5;
    int lsum = 0;
    #pragma unroll
    for (int i = 0; i < 5; ++i) lsum += cnt[lo + i];
    sh[t] = lsum;
    __syncthreads();
    for (int off = 1; off < 1024; off <<= 1) {
        int v = sh[t];
        int o = (t >= off) ? sh[t - off] : 0;
        __syncthreads();
        sh[t] = v + o;
        __syncthreads();
    }
    int running = sh[t] - lsum;  // exclusive prefix of this thread's chunk
    int* I0 = (int*)(ws + OFF_I);
    int* starts = I0 + I_STARTS;
    int* cursor = I0 + I_CURSOR;
    float* nums = ws + OFF_NUMS;
    #pragma unroll
    for (int i = 0; i < 5; ++i) {
        int c = lo + i;
        if (c < C) {
            int k = cnt[c];
            starts[c] = running;
            cursor[c] = running;
            nums[c] = (float)k;
            running += k;
        }
    }
    if (t == 0) starts[C] = M;
}

__global__ void k_scatter(const int* __restrict__ labels, float* __restrict__ ws) {
    int m = blockIdx.x * blockDim.x + threadIdx.x;
    if (m < M) {
        int* I0 = (int*)(ws + OFF_I);
        int pos = atomicAdd(&I0[I_CURSOR + labels[m]], 1);
        I0[I_PERM + pos] = m;
    }
}

// one block per class; thread t owns column t; rows read fully coalesced
__global__ __launch_bounds__(256) void k_gsum(const float* __restrict__ feats,
                                              float* __restrict__ ws) {
    const int c = blockIdx.x;
    const int t = threadIdx.x;
    const int* I0 = (const int*)(ws + OFF_I);
    const int* starts = I0 + I_STARTS;
    const int* perm = I0 + I_PERM;
    int s = starts[c], e = starts[c + 1];
    float acc = 0.0f;
    int r = s;
    for (; r + 3 < e; r += 4) {
        float v0 = feats[(size_t)perm[r] * D + t];
        float v1 = feats[(size_t)perm[r + 1] * D + t];
        float v2 = feats[(size_t)perm[r + 2] * D + t];
        float v3 = feats[(size_t)perm[r + 3] * D + t];
        acc += (v0 + v1) + (v2 + v3);
    }
    for (; r < e; ++r) acc += feats[(size_t)perm[r] * D + t];
    ws[OFF_G + (size_t)c * D + t] = acc;
}

// ---------------- L2-normalize the batch inputs ------------------------------
__global__ void k_normalize(const float* __restrict__ in, float* __restrict__ ws) {
    int b = blockIdx.x;
    int t = threadIdx.x;
    float v = in[b * D + t];
    float sq = v * v;
    #pragma unroll
    for (int o = 32; o; o >>= 1) sq += __shfl_down(sq, o, 64);
    __shared__ float s[4];
    if ((t & 63) == 0) s[t >> 6] = sq;
    __syncthreads();
    float norm = sqrtf(s[0] + s[1] + s[2] + s[3]);
    float inv = 1.0f / fmaxf(norm, 1e-12f);
    ws[OFF_X + b * D + t] = v * inv;
}

// ---- gemm over (X @ G^T)*scale, fused masked-exp row partial sums ----------
#define BT 64
#define CT 64
#define KT 64
__global__ __launch_bounds__(256) void k_gemm(float* __restrict__ ws) {
    const float* X = ws + OFF_X;
    const float* Gm = ws + OFF_G;
    const float* nums = ws + OFF_NUMS;
    float* Spart = ws + OFF_SPART;

    __shared__ __align__(16) float xs[KT][BT + 4];
    __shared__ __align__(16) float gs[KT][CT + 4];

    const int c0 = blockIdx.x * CT;
    const int b0 = blockIdx.y * BT;
    const int t = threadIdx.x;
    const int tx = t & 15, ty = t >> 4;

    float acc[4][4] = {};

    for (int k0 = 0; k0 < D; k0 += KT) {
        for (int i = t; i < BT * KT; i += 256) {
            int r = i >> 6;
            int k = i & 63;
            xs[k][r] = X[(b0 + r) * D + k0 + k];
        }
        for (int i = t; i < CT * KT; i += 256) {
            int r = i >> 6;
            int k = i & 63;
            int c = c0 + r;
            gs[k][r] = (c < C) ? Gm[(size_t)c * D + k0 + k] : 0.0f;
        }
        __syncthreads();
        #pragma unroll 8
        for (int k = 0; k < KT; ++k) {
            const float4 av = *reinterpret_cast<const float4*>(&xs[k][ty * 4]);
            const float4 bv = *reinterpret_cast<const float4*>(&gs[k][tx * 4]);
            const float a[4] = {av.x, av.y, av.z, av.w};
            const float bb[4] = {bv.x, bv.y, bv.z, bv.w};
            #pragma unroll
            for (int i = 0; i < 4; ++i)
                #pragma unroll
                for (int j = 0; j < 4; ++j)
                    acc[i][j] += a[i] * bb[j];
        }
        __syncthreads();
    }

    // epilogue: masked exp row-sums over this block's 64-col slice
    float scale[4];
    bool ok[4];
    #pragma unroll
    for (int j = 0; j < 4; ++j) {
        int c = c0 + tx * 4 + j;
        if (c < C) {
            float n = nums[c];
            ok[j] = (n > 0.0f);
            scale[j] = 1.0f / (TEMPF * (n > 0.0f ? n : 1.0f));
        } else {
            ok[j] = false;
            scale[j] = 0.0f;
        }
    }
    #pragma unroll
    for (int i = 0; i < 4; ++i) {
        float s = 0.0f;
        #pragma unroll
        for (int j = 0; j < 4; ++j) {
            if (ok[j]) s += expf(acc[i][j] * scale[j]);
        }
        #pragma unroll
        for (int o = 1; o < 16; o <<= 1) s += __shfl_xor(s, o, 64);
        if (tx == 0) {
            Spart[(size_t)(b0 + ty * 4 + i) * SPITCH + blockIdx.x] = s;
        }
    }
}

// ---- final: target logit via direct dot, NLL, mean --------------------------
__global__ __launch_bounds__(256) void k_final(const int* __restrict__ indexes,
                                               const int* __restrict__ labels,
                                               float* __restrict__ ws,
                                               float* __restrict__ out) {
    const int b = threadIdx.x;  // 256 threads, one per batch row
    const float* X = ws + OFF_X;
    const float* Gm = ws + OFF_G;
    const float* nums = ws + OFF_NUMS;
    const float* Spart = ws + OFF_SPART;

    int tgt = labels[indexes[b]];
    // dot(x[b], G[tgt])
    float dot = 0.0f;
    const float* xr = X + (size_t)b * D;
    const float* gr = Gm + (size_t)tgt * D;
    #pragma unroll 4
    for (int d = 0; d < D; ++d) dot += xr[d] * gr[d];
    float n = nums[tgt];
    float sim_t = dot / (TEMPF * (n > 0.0f ? n : 1.0f));

    float S = 0.0f;
    #pragma unroll 4
    for (int cb = 0; cb < NCB; ++cb) S += Spart[(size_t)b * SPITCH + cb];

    float p = expf(sim_t) / (S + EPSF) + EPSF;
    float l = -logf(p);

    #pragma unroll
    for (int o = 32; o; o >>= 1) l += __shfl_down(l, o, 64);
    __shared__ float sh[4];
    if ((b & 63) == 0) sh[b >> 6] = l;
    __syncthreads();
    if (b == 0) out[0] = (sh[0] + sh[1] + sh[2] + sh[3]) * (1.0f / B);
}

extern "C" void kernel_launch(void* const* d_in, const int* in_sizes, int n_in,
                              void* d_out, int out_size, void* d_ws, size_t ws_size,
                              hipStream_t stream) {
    const float* inputs = (const float*)d_in[0];
    const int* indexes = (const int*)d_in[1];
    const float* feats = (const float*)d_in[2];
    const int* labels = (const int*)d_in[3];
    float* ws = (float*)d_ws;
    float* out = (float*)d_out;

    k_normalize<<<B, 256, 0, stream>>>(inputs, ws);
    k_histscan<<<1, 1024, 0, stream>>>(labels, ws);
    k_scatter<<<(M + 255) / 256, 256, 0, stream>>>(labels, ws);
    k_gsum<<<C, 256, 0, stream>>>(feats, ws);
    k_gemm<<<dim3(NCB, B / BT), 256, 0, stream>>>(ws);
    k_final<<<1, 256, 0, stream>>>(indexes, labels, ws, out);
}

// Round 16
// 238.713 us; speedup vs baseline: 1.1767x; 1.1767x over previous
//
#include <hip/hip_runtime.h>
#include <math.h>

#define B 256
#define D 256
#define M 100000
#define C 5000
#define TEMPF 0.05f
#define EPSF 1e-6f
#define NCB 79          // ceil(C/64)

// ---- float ws layout (float offsets) ----
#define OFF_G 0                        // C*D = 1,280,000
#define OFF_NUMS (C * D)               // 5120
#define OFF_X (OFF_NUMS + 5120)        // B*D = 65,536
#define OFF_SPART (OFF_X + B * D)      // NCB*256 <= 20,480 (transposed: [cb][b])
#define OFF_STGT (OFF_SPART + 20480)   // 256 target logits
#define OFF_I (OFF_STGT + 256)         // int region (float-offset)
// ---- int region (int offsets from OFF_I) ----
#define I_COUNTS 0                     // 5120
#define I_STARTS 5120                  // 5121
#define I_CURSOR (5120 + 5121)         // 5120
#define I_TGT (5120 + 5121 + 5120)     // 256
#define I_PERM (I_TGT + 256)           // M
#define I_TOTAL (I_PERM + M)

// ---- normalize + fold in: counts zeroing, target precompute ----------------
__global__ void k_normalize(const float* __restrict__ in,
                            const int* __restrict__ indexes,
                            const int* __restrict__ labels,
                            float* __restrict__ ws) {
    int b = blockIdx.x;
    int t = threadIdx.x;
    int* I0 = (int*)(ws + OFF_I);
    if (t < 20) I0[I_COUNTS + b * 20 + t] = 0;          // 256*20 = 5120
    if (t == 0) I0[I_TGT + b] = labels[indexes[b]];
    float v = in[b * D + t];
    float sq = v * v;
    #pragma unroll
    for (int o = 32; o; o >>= 1) sq += __shfl_down(sq, o, 64);
    __shared__ float s[4];
    if ((t & 63) == 0) s[t >> 6] = sq;
    __syncthreads();
    float norm = sqrtf(s[0] + s[1] + s[2] + s[3]);
    float inv = 1.0f / fmaxf(norm, 1e-12f);
    ws[OFF_X + b * D + t] = v * inv;
}

__global__ void k_hist(const int* __restrict__ labels, float* __restrict__ ws) {
    int m = blockIdx.x * blockDim.x + threadIdx.x;
    if (m < M) {
        int* counts = (int*)(ws + OFF_I) + I_COUNTS;
        atomicAdd(&counts[labels[m]], 1);
    }
}

__global__ void k_scan(float* __restrict__ ws) {
    int* I0 = (int*)(ws + OFF_I);
    int* counts = I0 + I_COUNTS;
    int* starts = I0 + I_STARTS;
    int* cursor = I0 + I_CURSOR;
    float* nums = ws + OFF_NUMS;
    const int t = threadIdx.x;
    const int CH = 20;  // 256*20 = 5120 >= C
    int lo = t * CH;
    int lsum = 0;
    for (int i = 0; i < CH; ++i) lsum += counts[lo + i];
    __shared__ int sh[256];
    sh[t] = lsum;
    __syncthreads();
    for (int off = 1; off < 256; off <<= 1) {
        int v = sh[t];
        int o = (t >= off) ? sh[t - off] : 0;
        __syncthreads();
        sh[t] = v + o;
        __syncthreads();
    }
    int running = sh[t] - lsum;
    for (int i = 0; i < CH; ++i) {
        int c = lo + i;
        if (c < C) {
            int k = counts[c];
            starts[c] = running;
            cursor[c] = running;
            nums[c] = (float)k;
            running += k;
        }
    }
    if (t == 0) starts[C] = M;
}

__global__ void k_scatter(const int* __restrict__ labels, float* __restrict__ ws) {
    int m = blockIdx.x * blockDim.x + threadIdx.x;
    if (m < M) {
        int* I0 = (int*)(ws + OFF_I);
        int pos = atomicAdd(&I0[I_CURSOR + labels[m]], 1);
        I0[I_PERM + pos] = m;
    }
}

// one block per class; thread t owns column t; rows read fully coalesced
__global__ __launch_bounds__(256) void k_gsum(const float* __restrict__ feats,
                                              float* __restrict__ ws) {
    const int c = blockIdx.x;
    const int t = threadIdx.x;
    const int* I0 = (const int*)(ws + OFF_I);
    const int* starts = I0 + I_STARTS;
    const int* perm = I0 + I_PERM;
    int s = starts[c], e = starts[c + 1];
    float acc = 0.0f;
    int r = s;
    for (; r + 3 < e; r += 4) {
        float v0 = feats[(size_t)perm[r] * D + t];
        float v1 = feats[(size_t)perm[r + 1] * D + t];
        float v2 = feats[(size_t)perm[r + 2] * D + t];
        float v3 = feats[(size_t)perm[r + 3] * D + t];
        acc += (v0 + v1) + (v2 + v3);
    }
    for (; r < e; ++r) acc += feats[(size_t)perm[r] * D + t];
    ws[OFF_G + (size_t)c * D + t] = acc;
}

// ---- gemm (X @ G^T)*scale, fused masked-exp row sums + target capture ------
#define BT 64
#define CT 64
#define KT 64
__global__ __launch_bounds__(256) void k_gemm(float* __restrict__ ws) {
    const float* X = ws + OFF_X;
    const float* Gm = ws + OFF_G;
    const float* nums = ws + OFF_NUMS;
    float* Spart = ws + OFF_SPART;
    float* Stgt = ws + OFF_STGT;
    const int* tgt = (const int*)(ws + OFF_I) + I_TGT;

    __shared__ __align__(16) float xs[KT][BT + 4];
    __shared__ __align__(16) float gs[KT][CT + 4];

    const int c0 = blockIdx.x * CT;
    const int b0 = blockIdx.y * BT;
    const int t = threadIdx.x;
    const int tx = t & 15, ty = t >> 4;

    float acc[4][4] = {};

    for (int k0 = 0; k0 < D; k0 += KT) {
        for (int i = t; i < BT * KT; i += 256) {
            int r = i >> 6;
            int k = i & 63;
            xs[k][r] = X[(b0 + r) * D + k0 + k];
        }
        for (int i = t; i < CT * KT; i += 256) {
            int r = i >> 6;
            int k = i & 63;
            int c = c0 + r;
            gs[k][r] = (c < C) ? Gm[(size_t)c * D + k0 + k] : 0.0f;
        }
        __syncthreads();
        #pragma unroll 8
        for (int k = 0; k < KT; ++k) {
            const float4 av = *reinterpret_cast<const float4*>(&xs[k][ty * 4]);
            const float4 bv = *reinterpret_cast<const float4*>(&gs[k][tx * 4]);
            const float a[4] = {av.x, av.y, av.z, av.w};
            const float bb[4] = {bv.x, bv.y, bv.z, bv.w};
            #pragma unroll
            for (int i = 0; i < 4; ++i)
                #pragma unroll
                for (int j = 0; j < 4; ++j)
                    acc[i][j] += a[i] * bb[j];
        }
        __syncthreads();
    }

    // per-column scale/mask for this thread's 4 columns
    float scale[4];
    bool ok[4];
    #pragma unroll
    for (int j = 0; j < 4; ++j) {
        int c = c0 + tx * 4 + j;
        if (c < C) {
            float n = nums[c];
            ok[j] = (n > 0.0f);
            scale[j] = 1.0f / (TEMPF * (n > 0.0f ? n : 1.0f));
        } else {
            ok[j] = false;
            scale[j] = 0.0f;
        }
    }
    #pragma unroll
    for (int i = 0; i < 4; ++i) {
        const int row = b0 + ty * 4 + i;
        // capture target logit if this thread owns row's target column
        int off = tgt[row] - c0;
        if (off >= 0 && off < CT && (off >> 2) == tx) {
            int j = off & 3;
            Stgt[row] = acc[i][j] * scale[j];
        }
        // masked exp row-sum over this block's 64-col slice
        float s = 0.0f;
        #pragma unroll
        for (int j = 0; j < 4; ++j) {
            if (ok[j]) s += expf(acc[i][j] * scale[j]);
        }
        #pragma unroll
        for (int o = 1; o < 16; o <<= 1) s += __shfl_xor(s, o, 64);
        if (tx == 0) {
            Spart[(size_t)blockIdx.x * 256 + row] = s;  // transposed: [cb][b]
        }
    }
}

// ---- final: S reduce (coalesced), NLL, mean ---------------------------------
__global__ __launch_bounds__(256) void k_final(float* __restrict__ ws,
                                               float* __restrict__ out) {
    const int b = threadIdx.x;
    const float* Spart = ws + OFF_SPART;
    float S = 0.0f;
    #pragma unroll 4
    for (int cb = 0; cb < NCB; ++cb) S += Spart[(size_t)cb * 256 + b];
    float sim_t = ws[OFF_STGT + b];
    float p = expf(sim_t) / (S + EPSF) + EPSF;
    float l = -logf(p);
    #pragma unroll
    for (int o = 32; o; o >>= 1) l += __shfl_down(l, o, 64);
    __shared__ float sh[4];
    if ((b & 63) == 0) sh[b >> 6] = l;
    __syncthreads();
    if (b == 0) out[0] = (sh[0] + sh[1] + sh[2] + sh[3]) * (1.0f / B);
}

extern "C" void kernel_launch(void* const* d_in, const int* in_sizes, int n_in,
                              void* d_out, int out_size, void* d_ws, size_t ws_size,
                              hipStream_t stream) {
    const float* inputs = (const float*)d_in[0];
    const int* indexes = (const int*)d_in[1];
    const float* feats = (const float*)d_in[2];
    const int* labels = (const int*)d_in[3];
    float* ws = (float*)d_ws;
    float* out = (float*)d_out;

    k_normalize<<<B, 256, 0, stream>>>(inputs, indexes, labels, ws);
    k_hist<<<(M + 255) / 256, 256, 0, stream>>>(labels, ws);
    k_scan<<<1, 256, 0, stream>>>(ws);
    k_scatter<<<(M + 255) / 256, 256, 0, stream>>>(labels, ws);
    k_gsum<<<C, 256, 0, stream>>>(feats, ws);
    k_gemm<<<dim3(NCB, B / BT), 256, 0, stream>>>(ws);
    k_final<<<1, 256, 0, stream>>>(ws, out);
}